// Round 11
// baseline (1116.311 us; speedup 1.0000x reference)
//
#include <hip/hip_runtime.h>
#include <hip/hip_fp16.h>

#define IN_DIM 23
#define HID 128
#define OUTD 64
#define NGR 64
#define NPART 32
#define FILL_GRP 8
#define FB_DIM 32    // feat padded to 32 bf16 = 64B aligned rows
#define PH_STRIDE 136  // 16 rows x 136 bf16 (16B-aligned, bank-spread)

typedef __attribute__((ext_vector_type(8))) short bf16x8;
typedef __attribute__((ext_vector_type(4))) float f32x4;

static __device__ __forceinline__ unsigned short f2bf(float x) {
    unsigned u = __float_as_uint(x);
    unsigned r = (u + 0x7FFFu + ((u >> 16) & 1u)) >> 16;   // RNE
    return (unsigned short)r;
}
static __device__ __forceinline__ float bf2f(unsigned short u) {
    return __uint_as_float((unsigned)u << 16);             // exact
}

// ---------------- A: fused src+dst histogram (one edge-list pass) ------------
__global__ __launch_bounds__(256) void k_hist(
    const int* __restrict__ dst, const int* __restrict__ src,
    int* __restrict__ degi, int* __restrict__ sdegi, int n_edges)
{
    int e = blockIdx.x * 256 + threadIdx.x;
    if (e < n_edges) {
        atomicAdd(&degi[dst[e]], 1);
        atomicAdd(&sdegi[src[e]], 1);
    }
}

// ---------------- A2: transcode feat0 -> bf16 padded rows --------------------
__global__ __launch_bounds__(256) void k_featb(
    const float* __restrict__ feat0, unsigned short* __restrict__ featb,
    int n_nodes)
{
    int i = blockIdx.x * 256 + threadIdx.x;
    if (i >= n_nodes * FB_DIM) return;
    int v = i >> 5, d = i & (FB_DIM - 1);
    float x = (d < IN_DIM) ? feat0[(size_t)v * IN_DIM + d] : 0.f;
    featb[i] = f2bf(x);
}

// ---------------- A3: weight transpose+pad to bf16 MFMA B-operand layout -----
__global__ __launch_bounds__(256) void k_wprep(
    const float* __restrict__ W1, const float* __restrict__ W2,
    unsigned short* __restrict__ W1t, unsigned short* __restrict__ W2t)
{
    int i = blockIdx.x * 256 + threadIdx.x;
    if (i < HID * 32) {
        int h = i >> 5, d = i & 31;
        W1t[i] = f2bf((d < IN_DIM) ? W1[d * HID + h] : 0.f);
    } else if (i < HID * 32 + OUTD * HID) {
        int j = i - HID * 32;
        int o = j >> 7, k = j & 127;
        W2t[j] = f2bf(W2[k * OUTD + o]);
    }
}

// ---------------- A4: per-dst packed payload table: (gid<<16)|fp16(1/(deg+1))
__global__ __launch_bounds__(256) void k_pwg(
    const int* __restrict__ degi, const int* __restrict__ gids,
    unsigned* __restrict__ pwg, int n_nodes)
{
    int v = blockIdx.x * 256 + threadIdx.x;
    if (v >= n_nodes) return;
    float w = 1.0f / ((float)degi[v] + 1.0f);
    __half h = __float2half(w);
    pwg[v] = ((unsigned)gids[v] << 16) | (unsigned)__half_as_ushort(h);
}

// ---------------- B1: per-block local exclusive scan + block totals ----------
__global__ __launch_bounds__(256) void k_scan_local(
    const int* __restrict__ degi, int* __restrict__ local,
    int* __restrict__ bsum, int n_nodes)
{
    int base = blockIdx.x * 1024 + threadIdx.x * 4;
    int4 d = {0, 0, 0, 0};
    if (base + 3 < n_nodes) {
        d = *(const int4*)&degi[base];
    } else {
        if (base + 0 < n_nodes) d.x = degi[base + 0];
        if (base + 1 < n_nodes) d.y = degi[base + 1];
        if (base + 2 < n_nodes) d.z = degi[base + 2];
        if (base + 3 < n_nodes) d.w = degi[base + 3];
    }
    int tsum = d.x + d.y + d.z + d.w;
    int lane = threadIdx.x & 63;
    int wave = threadIdx.x >> 6;
    int s = tsum;
#pragma unroll
    for (int off = 1; off < 64; off <<= 1) {
        int v = __shfl_up(s, off);
        if (lane >= off) s += v;
    }
    __shared__ int wtot[4];
    if (lane == 63) wtot[wave] = s;
    __syncthreads();
    int woff = 0;
#pragma unroll
    for (int i = 0; i < 4; ++i) woff += (i < wave) ? wtot[i] : 0;
    int excl = woff + s - tsum;
    int l0 = excl;
    int l1 = l0 + d.x;
    int l2 = l1 + d.y;
    int l3 = l2 + d.z;
    if (base + 3 < n_nodes) {
        *(int4*)&local[base] = make_int4(l0, l1, l2, l3);
    } else {
        if (base + 0 < n_nodes) local[base + 0] = l0;
        if (base + 1 < n_nodes) local[base + 1] = l1;
        if (base + 2 < n_nodes) local[base + 2] = l2;
        if (base + 3 < n_nodes) local[base + 3] = l3;
    }
    if (threadIdx.x == 255) bsum[blockIdx.x] = excl + tsum;
}

// ---------------- B2: scan the (<=1024) block totals -------------------------
__global__ __launch_bounds__(1024) void k_scan_bsum(
    const int* __restrict__ bsum, int* __restrict__ boff,
    int* __restrict__ rowstart, int nb, int n_nodes, int n_edges)
{
    __shared__ int lds[1024];
    int t = threadIdx.x;
    lds[t] = (t < nb) ? bsum[t] : 0;
    __syncthreads();
    for (int off = 1; off < 1024; off <<= 1) {
        int v = (t >= off) ? lds[t - off] : 0;
        __syncthreads();
        lds[t] += v;
        __syncthreads();
    }
    if (t < nb) boff[t] = (t == 0) ? 0 : lds[t - 1];
    if (t == 0) rowstart[n_nodes] = n_edges;
}

// ---------------- B3: apply block offsets -> rowstart, cursor ----------------
__global__ __launch_bounds__(256) void k_scan_apply(
    const int* __restrict__ local, const int* __restrict__ boff,
    int* __restrict__ rowstart, int* __restrict__ cursor, int n_nodes)
{
    int base = blockIdx.x * 1024 + threadIdx.x * 4;
    int off = boff[blockIdx.x];
    if (base + 3 < n_nodes) {
        int4 l = *(const int4*)&local[base];
        int4 r = make_int4(l.x + off, l.y + off, l.z + off, l.w + off);
        *(int4*)&rowstart[base] = r;
        *(int4*)&cursor[base] = r;
    } else {
        for (int i = 0; i < 4; ++i) {
            if (base + i < n_nodes) {
                int r = local[base + i] + off;
                rowstart[base + i] = r;
                cursor[base + i] = r;
            }
        }
    }
}

// ---------------- C: FUSED dual CSR fill, XCD-grouped ------------------------
// One 8-pass scan serves both CSRs: pass grp handles dst-range writes (eidx)
// and src-range writes (ewg_i). All written slices (~800KB each) + cursor
// slices stay in the pass-owning XCD's L2.
__global__ __launch_bounds__(256) void k_fillb(
    const int* __restrict__ src, const int* __restrict__ dst,
    int* __restrict__ cursor, int* __restrict__ scursor,
    int* __restrict__ eidx, int* __restrict__ ewg_i, int n_edges, int n_nodes)
{
    int grp = blockIdx.x & (FILL_GRP - 1);
    int lo = (int)((long long)grp * n_nodes / FILL_GRP);
    int hi = (int)((long long)(grp + 1) * n_nodes / FILL_GRP);
    int nblk = gridDim.x >> 3;
    int bid = blockIdx.x >> 3;
    for (int e = bid * 256 + threadIdx.x; e < n_edges; e += nblk * 256) {
        int s = src[e];
        int v = dst[e];
        if (v >= lo && v < hi) {
            int pos = atomicAdd(&cursor[v], 1);
            eidx[pos] = s;
        }
        if (s >= lo && s < hi) {
            int pos = atomicAdd(&scursor[s], 1);
            ewg_i[pos] = v;
        }
    }
}

// ---------------- C2: resolve src-CSR payload: ewg[i] = pwg[dst_index] -------
// Sequential read of ewg_i, random read of L2-resident 400KB pwg, seq write.
__global__ __launch_bounds__(256) void k_resolve(
    const int* __restrict__ ewg_i, const unsigned* __restrict__ pwg,
    unsigned* __restrict__ ewg, int n_edges)
{
    int i = blockIdx.x * 256 + threadIdx.x;
    if (i < n_edges) ewg[i] = pwg[ewg_i[i]];
}

// ---------------- D: layer-1 gather, QUAD-PER-NODE ---------------------------
__global__ __launch_bounds__(256) void k_agg1(
    const int* __restrict__ rowstart, const int* __restrict__ eidx,
    const unsigned* __restrict__ fbd, const float* __restrict__ feat0,
    unsigned* __restrict__ hnbd, int n_nodes)
{
    int lane = threadIdx.x & 63;
    int quad = lane >> 4, l15 = lane & 15;
    int wglob = (int)((blockIdx.x * 256u + threadIdx.x) >> 6);
    int v = wglob * 4 + quad;
    if (v >= n_nodes) return;
    int e0 = rowstart[v], e1 = rowstart[v + 1];
    int nedge = e1 - e0;
    float a0 = 0.f, a1 = 0.f;
    for (int base = 0; base < nedge; base += 16) {
        int cnt = min(16, nedge - base);
        int idx = 0;
        if (l15 < cnt) idx = eidx[e0 + base + l15];
        unsigned uu[16];
#pragma unroll
        for (int j = 0; j < 16; ++j) {
            int s = __shfl(idx, quad * 16 + min(j, cnt - 1));
            uu[j] = 0u;
            if (j < cnt) uu[j] = fbd[(size_t)s * 16 + l15];
        }
#pragma unroll
        for (int j = 0; j < 16; ++j) {
            a0 += bf2f((unsigned short)(uu[j] & 0xFFFF));
            a1 += bf2f((unsigned short)(uu[j] >> 16));
        }
    }
    int d0 = 2 * l15, d1 = d0 + 1;
    float f0 = (d0 < IN_DIM) ? feat0[(size_t)v * IN_DIM + d0] : 0.f;
    float f1 = (d1 < IN_DIM) ? feat0[(size_t)v * IN_DIM + d1] : 0.f;
    float inv = 1.0f / ((float)nedge + 1.0f);
    unsigned out = (unsigned)f2bf((a0 + f0) * inv)
                 | ((unsigned)f2bf((a1 + f1) * inv) << 16);
    hnbd[(size_t)v * 16 + l15] = out;
}

// ---------------- E: MFMA node transform (unchanged) -------------------------
__global__ __launch_bounds__(256) void k_node(
    const unsigned short* __restrict__ hnb, const unsigned short* __restrict__ W1t,
    const float* __restrict__ b1, const unsigned short* __restrict__ W2t,
    unsigned short* __restrict__ m1, int n_nodes)
{
    __shared__ unsigned short ph[4][16 * PH_STRIDE];
    int wave = threadIdx.x >> 6, lane = threadIdx.x & 63;
    int quad = lane >> 4, l15 = lane & 15;
    const f32x4 z4 = {0.f, 0.f, 0.f, 0.f};

    float bb[8];
#pragma unroll
    for (int t = 0; t < 8; ++t) bb[t] = b1[t * 16 + l15];

    for (int v0 = blockIdx.x * 64 + wave * 16; v0 < n_nodes; v0 += gridDim.x * 64) {
        bf16x8 aH = {0, 0, 0, 0, 0, 0, 0, 0};
        int vA = v0 + l15;
        if (vA < n_nodes) aH = *(const bf16x8*)&hnb[(size_t)vA * FB_DIM + quad * 8];
        f32x4 c1[8];
#pragma unroll
        for (int t = 0; t < 8; ++t) {
            bf16x8 bw = *(const bf16x8*)&W1t[(t * 16 + l15) * 32 + quad * 8];
            c1[t] = __builtin_amdgcn_mfma_f32_16x16x32_bf16(aH, bw, z4, 0, 0, 0);
        }
        float ssq[4] = {0.f, 0.f, 0.f, 0.f};
#pragma unroll
        for (int t = 0; t < 8; ++t) {
#pragma unroll
            for (int r = 0; r < 4; ++r) {
                float x = fmaxf(c1[t][r] + bb[t], 0.f);
                c1[t][r] = x;
                ssq[r] += x * x;
            }
        }
#pragma unroll
        for (int off = 1; off < 16; off <<= 1) {
#pragma unroll
            for (int r = 0; r < 4; ++r) ssq[r] += __shfl_xor(ssq[r], off);
        }
        float inv[4];
#pragma unroll
        for (int r = 0; r < 4; ++r) inv[r] = 1.0f / fmaxf(sqrtf(ssq[r]), 1e-12f);
#pragma unroll
        for (int t = 0; t < 8; ++t)
#pragma unroll
            for (int r = 0; r < 4; ++r)
                ph[wave][(quad * 4 + r) * PH_STRIDE + t * 16 + l15] =
                    f2bf(c1[t][r] * inv[r]);
        f32x4 c2[4] = {z4, z4, z4, z4};
#pragma unroll
        for (int ks = 0; ks < 4; ++ks) {
            bf16x8 aP = *(const bf16x8*)&ph[wave][l15 * PH_STRIDE + ks * 32 + quad * 8];
#pragma unroll
            for (int tn = 0; tn < 4; ++tn) {
                bf16x8 bw = *(const bf16x8*)&W2t[(tn * 16 + l15) * HID + ks * 32 + quad * 8];
                c2[tn] = __builtin_amdgcn_mfma_f32_16x16x32_bf16(aP, bw, c2[tn], 0, 0, 0);
            }
        }
#pragma unroll
        for (int tn = 0; tn < 4; ++tn)
#pragma unroll
            for (int r = 0; r < 4; ++r) {
                int v = v0 + quad * 4 + r;
                if (v < n_nodes) m1[(size_t)v * OUTD + tn * 16 + l15] = f2bf(c2[tn][r]);
            }
    }
}

// ---------------- F: layer-2 SRC-MAJOR STREAMING + graph mean (fixed) --------
// Per edge: v_readlane (SALU, uniform idx) + ~6 VALU + 1 wave-wide LDS atomic.
// No bpermute, no dependent LDS chain; 8 independent edge bodies per block.
// Lanes >= cnt carry payload 0 -> add exactly 0.0 to graph 0 (harmless).
__global__ __launch_bounds__(256) void k_agg2s(
    const int* __restrict__ srowstart, const unsigned* __restrict__ ewg,
    const unsigned* __restrict__ m1d, const unsigned* __restrict__ pwg,
    float* __restrict__ gpart, float* __restrict__ gcnt, int n_nodes, int chunk)
{
    __shared__ float lsum[NGR * OUTD];
    __shared__ float lcnt[NGR];
    for (int i = threadIdx.x; i < NGR * OUTD; i += 256) lsum[i] = 0.f;
    if (threadIdx.x < NGR) lcnt[threadIdx.x] = 0.f;
    __syncthreads();

    int lane = threadIdx.x & 63;
    int w = (int)((blockIdx.x * 256u + threadIdx.x) >> 6);
    int v0 = w * chunk;
    int vcnt = min(chunk, n_nodes - v0);
    if (vcnt > 0) {
        // preload chunk rowstarts + self payloads into lanes (chunk <= 63)
        int rs = 0;
        unsigned pw = 0;
        if (lane <= vcnt) rs = srowstart[v0 + lane];
        if (lane < vcnt) pw = pwg[v0 + lane];
        for (int j = 0; j < vcnt; ++j) {      // j is wave-uniform -> readlane ok
            int v = v0 + j;
            int s0 = __builtin_amdgcn_readlane(rs, j);
            int s1 = __builtin_amdgcn_readlane(rs, j + 1);
            unsigned pv = (unsigned)__builtin_amdgcn_readlane((int)pw, j);
            // sequential m1 row read: dword lane>>1, bf16 half lane&1
            unsigned um = m1d[(size_t)v * 32 + (lane >> 1)];
            float val = bf2f((unsigned short)((lane & 1) ? (um >> 16) : (um & 0xFFFF)));
            // self term: w_v * m1[v] -> graph g_v
            {
                float wv = __half2float(__ushort_as_half((unsigned short)(pv & 0xFFFF)));
                int g = (int)(pv >> 16);
                atomicAdd(&lsum[g * OUTD + lane], wv * val);
                if (lane == 0) atomicAdd(&lcnt[g], 1.0f);
            }
            // out-edges: payload streams sequentially; 8 edges per step
            for (int base = s0; base < s1; base += 64) {
                int cnt = min(64, s1 - base);
                unsigned we = 0;
                if (lane < cnt) we = ewg[base + lane];
                for (int t = 0; t < cnt; t += 8) {
#pragma unroll
                    for (int k = 0; k < 8; ++k) {
                        unsigned u = (unsigned)__builtin_amdgcn_readlane((int)we, t + k);
                        float wt = __half2float(__ushort_as_half((unsigned short)(u & 0xFFFF)));
                        int g = (int)(u >> 16);
                        atomicAdd(&lsum[g * OUTD + lane], wt * val);
                    }
                }
            }
        }
    }
    __syncthreads();
    float* gp = gpart + (size_t)(blockIdx.x & (NPART - 1)) * NGR * OUTD;
    for (int i = threadIdx.x; i < NGR * OUTD; i += 256) atomicAdd(&gp[i], lsum[i]);
    if (threadIdx.x < NGR) atomicAdd(&gcnt[threadIdx.x], lcnt[threadIdx.x]);
}

// ---------------- G: finalize: reduce partials, mean + b2 --------------------
__global__ __launch_bounds__(256) void k_final(
    const float* __restrict__ gpart, const float* __restrict__ gcnt,
    const float* __restrict__ b2, float* __restrict__ out)
{
    int i = blockIdx.x * 256 + threadIdx.x;
    if (i >= NGR * OUTD) return;
    int g = i >> 6, d = i & 63;
    float s = 0.f;
#pragma unroll
    for (int p = 0; p < NPART; ++p) s += gpart[(size_t)p * NGR * OUTD + i];
    float c = gcnt[g];
    out[i] = (c > 0.f) ? (s / c + b2[d]) : 0.f;
}

extern "C" void kernel_launch(void* const* d_in, const int* in_sizes, int n_in,
                              void* d_out, int out_size, void* d_ws, size_t ws_size,
                              hipStream_t stream) {
    const float* feat0 = (const float*)d_in[0];
    const float* W1    = (const float*)d_in[1];
    const float* b1    = (const float*)d_in[2];
    const float* W2    = (const float*)d_in[3];
    const float* b2    = (const float*)d_in[4];
    const int*   src   = (const int*)d_in[5];
    const int*   dst   = (const int*)d_in[6];
    const int*   gids  = (const int*)d_in[7];
    int n_edges = in_sizes[5];
    int n_nodes = in_sizes[7];

    int nb = (n_nodes + 1023) / 1024;

    // workspace: bf16 section (16B-aligned), then 4B section with the zeroed
    // block (degi|sdegi|gpart|gcnt) first.
    unsigned short* W1t = (unsigned short*)d_ws;
    unsigned short* W2t = W1t + HID * 32;
    unsigned short* hnb = W2t + (size_t)OUTD * HID;
    unsigned short* m1b = hnb + (size_t)n_nodes * FB_DIM;
    unsigned short* featb = m1b + (size_t)n_nodes * OUTD;
    int*   degi     = (int*)(featb + (size_t)n_nodes * FB_DIM);
    int*   sdegi    = degi + n_nodes;
    float* gpart    = (float*)(sdegi + n_nodes);
    float* gcnt     = gpart + (size_t)NPART * NGR * OUTD;
    int*   rowstart = (int*)(gcnt + NGR);
    int*   srowstart= rowstart + n_nodes + 1;
    int*   cursor   = srowstart + n_nodes + 1;
    int*   scursor  = cursor + n_nodes;
    int*   local    = scursor + n_nodes;
    int*   bsum     = local + n_nodes;
    int*   boff     = bsum + nb;
    int*   eidx     = boff + nb;
    int*   ewg_i    = eidx + n_edges;
    unsigned* ewg   = (unsigned*)(ewg_i + n_edges);
    unsigned* pwg   = ewg + n_edges;

    size_t zero_units = 2 * (size_t)n_nodes + (size_t)NPART * NGR * OUTD + NGR;
    hipMemsetAsync(degi, 0, zero_units * 4, stream);

    unsigned blkE = (unsigned)((n_edges + 255) / 256);
    k_hist<<<blkE, 256, 0, stream>>>(dst, src, degi, sdegi, n_edges);

    k_featb<<<(unsigned)(((long long)n_nodes * FB_DIM + 255) / 256), 256, 0, stream>>>(
        feat0, featb, n_nodes);
    k_wprep<<<(HID * 32 + OUTD * HID + 255) / 256, 256, 0, stream>>>(W1, W2, W1t, W2t);
    k_pwg<<<(n_nodes + 255) / 256, 256, 0, stream>>>(degi, gids, pwg, n_nodes);

    // dst-CSR scan
    k_scan_local<<<nb, 256, 0, stream>>>(degi, local, bsum, n_nodes);
    k_scan_bsum<<<1, 1024, 0, stream>>>(bsum, boff, rowstart, nb, n_nodes, n_edges);
    k_scan_apply<<<nb, 256, 0, stream>>>(local, boff, rowstart, cursor, n_nodes);
    // src-CSR scan (reuses local/bsum/boff temporaries)
    k_scan_local<<<nb, 256, 0, stream>>>(sdegi, local, bsum, n_nodes);
    k_scan_bsum<<<1, 1024, 0, stream>>>(bsum, boff, srowstart, nb, n_nodes, n_edges);
    k_scan_apply<<<nb, 256, 0, stream>>>(local, boff, srowstart, scursor, n_nodes);

    k_fillb<<<2048, 256, 0, stream>>>(src, dst, cursor, scursor, eidx, ewg_i,
                                      n_edges, n_nodes);
    k_resolve<<<blkE, 256, 0, stream>>>(ewg_i, pwg, ewg, n_edges);

    unsigned blkA = (unsigned)((n_nodes + 15) / 16);
    k_agg1<<<blkA, 256, 0, stream>>>(rowstart, eidx, (const unsigned*)featb, feat0,
                                     (unsigned*)hnb, n_nodes);

    k_node<<<1024, 256, 0, stream>>>(hnb, W1t, b1, W2t, m1b, n_nodes);

    int NW = 2048 * 4;                       // waves in k_agg2s
    int chunk = (n_nodes + NW - 1) / NW;     // 13 for 100K nodes (must be <=63)
    k_agg2s<<<2048, 256, 0, stream>>>(srowstart, ewg, (const unsigned*)m1b, pwg,
                                      gpart, gcnt, n_nodes, chunk);

    k_final<<<(NGR * OUTD + 255) / 256, 256, 0, stream>>>(gpart, gcnt, b2, (float*)d_out);
}

// Round 12
// 822.399 us; speedup vs baseline: 1.3574x; 1.3574x over previous
//
#include <hip/hip_runtime.h>

#define IN_DIM 23
#define HID 128
#define OUTD 64
#define NGR 64
#define FILL_GRP 8
#define FB_DIM 32      // feat padded to 32 bf16 = 64B aligned rows
#define PH_STRIDE 136  // k_node LDS stride
#define WSCALE 8388608.0f   // 2^23 fixed-point scale for W
#define GEMM_BLKS 256

typedef __attribute__((ext_vector_type(8))) short bf16x8;
typedef __attribute__((ext_vector_type(4))) float f32x4;

static __device__ __forceinline__ unsigned short f2bf(float x) {
    unsigned u = __float_as_uint(x);
    unsigned r = (u + 0x7FFFu + ((u >> 16) & 1u)) >> 16;   // RNE
    return (unsigned short)r;
}
static __device__ __forceinline__ float bf2f(unsigned short u) {
    return __uint_as_float((unsigned)u << 16);             // exact
}

// ---------------- A: dst in-degree histogram (native int atomics) ------------
__global__ __launch_bounds__(256) void k_hist(
    const int* __restrict__ dst, int* __restrict__ degi, int n_edges)
{
    int e = blockIdx.x * 256 + threadIdx.x;
    if (e < n_edges) atomicAdd(&degi[dst[e]], 1);
}

// ---------------- A2: transcode feat0 -> bf16 padded rows --------------------
__global__ __launch_bounds__(256) void k_featb(
    const float* __restrict__ feat0, unsigned short* __restrict__ featb,
    int n_nodes)
{
    int i = blockIdx.x * 256 + threadIdx.x;
    if (i >= n_nodes * FB_DIM) return;
    int v = i >> 5, d = i & (FB_DIM - 1);
    float x = (d < IN_DIM) ? feat0[(size_t)v * IN_DIM + d] : 0.f;
    featb[i] = f2bf(x);
}

// ---------------- A3: weight transpose+pad to bf16 MFMA B-operand layout -----
__global__ __launch_bounds__(256) void k_wprep(
    const float* __restrict__ W1, const float* __restrict__ W2,
    unsigned short* __restrict__ W1t, unsigned short* __restrict__ W2t)
{
    int i = blockIdx.x * 256 + threadIdx.x;
    if (i < HID * 32) {
        int h = i >> 5, d = i & 31;
        W1t[i] = f2bf((d < IN_DIM) ? W1[d * HID + h] : 0.f);
    } else if (i < HID * 32 + OUTD * HID) {
        int j = i - HID * 32;
        int o = j >> 7, k = j & 127;
        W2t[j] = f2bf(W2[k * OUTD + o]);
    }
}

// ---------------- A4: payload pack (gid<<24)|wint, W self-term, graph counts -
__global__ __launch_bounds__(256) void k_pwg(
    const int* __restrict__ degi, const int* __restrict__ gids,
    unsigned* __restrict__ pwg, int* __restrict__ Wint,
    int* __restrict__ gcnt_i, int n_nodes)
{
    int v = blockIdx.x * 256 + threadIdx.x;
    if (v >= n_nodes) return;
    float w = 1.0f / ((float)degi[v] + 1.0f);
    int wi = (int)rintf(w * WSCALE);        // <= 2^23, fits 24 bits
    int g = gids[v];
    pwg[v] = ((unsigned)g << 24) | (unsigned)wi;
    atomicAdd(&Wint[(size_t)v * NGR + g], wi);   // self term w_v -> graph g_v
    atomicAdd(&gcnt_i[g], 1);
}

// ---------------- B1: per-block local exclusive scan + block totals ----------
__global__ __launch_bounds__(256) void k_scan_local(
    const int* __restrict__ degi, int* __restrict__ local,
    int* __restrict__ bsum, int n_nodes)
{
    int base = blockIdx.x * 1024 + threadIdx.x * 4;
    int4 d = {0, 0, 0, 0};
    if (base + 3 < n_nodes) {
        d = *(const int4*)&degi[base];
    } else {
        if (base + 0 < n_nodes) d.x = degi[base + 0];
        if (base + 1 < n_nodes) d.y = degi[base + 1];
        if (base + 2 < n_nodes) d.z = degi[base + 2];
        if (base + 3 < n_nodes) d.w = degi[base + 3];
    }
    int tsum = d.x + d.y + d.z + d.w;
    int lane = threadIdx.x & 63;
    int wave = threadIdx.x >> 6;
    int s = tsum;
#pragma unroll
    for (int off = 1; off < 64; off <<= 1) {
        int v = __shfl_up(s, off);
        if (lane >= off) s += v;
    }
    __shared__ int wtot[4];
    if (lane == 63) wtot[wave] = s;
    __syncthreads();
    int woff = 0;
#pragma unroll
    for (int i = 0; i < 4; ++i) woff += (i < wave) ? wtot[i] : 0;
    int excl = woff + s - tsum;
    int l0 = excl;
    int l1 = l0 + d.x;
    int l2 = l1 + d.y;
    int l3 = l2 + d.z;
    if (base + 3 < n_nodes) {
        *(int4*)&local[base] = make_int4(l0, l1, l2, l3);
    } else {
        if (base + 0 < n_nodes) local[base + 0] = l0;
        if (base + 1 < n_nodes) local[base + 1] = l1;
        if (base + 2 < n_nodes) local[base + 2] = l2;
        if (base + 3 < n_nodes) local[base + 3] = l3;
    }
    if (threadIdx.x == 255) bsum[blockIdx.x] = excl + tsum;
}

// ---------------- B2: scan the (<=1024) block totals -------------------------
__global__ __launch_bounds__(1024) void k_scan_bsum(
    const int* __restrict__ bsum, int* __restrict__ boff,
    int* __restrict__ rowstart, int nb, int n_nodes, int n_edges)
{
    __shared__ int lds[1024];
    int t = threadIdx.x;
    lds[t] = (t < nb) ? bsum[t] : 0;
    __syncthreads();
    for (int off = 1; off < 1024; off <<= 1) {
        int v = (t >= off) ? lds[t - off] : 0;
        __syncthreads();
        lds[t] += v;
        __syncthreads();
    }
    if (t < nb) boff[t] = (t == 0) ? 0 : lds[t - 1];
    if (t == 0) rowstart[n_nodes] = n_edges;
}

// ---------------- B3: apply block offsets -> rowstart, cursor ----------------
__global__ __launch_bounds__(256) void k_scan_apply(
    const int* __restrict__ local, const int* __restrict__ boff,
    int* __restrict__ rowstart, int* __restrict__ cursor, int n_nodes)
{
    int base = blockIdx.x * 1024 + threadIdx.x * 4;
    int off = boff[blockIdx.x];
    if (base + 3 < n_nodes) {
        int4 l = *(const int4*)&local[base];
        int4 r = make_int4(l.x + off, l.y + off, l.z + off, l.w + off);
        *(int4*)&rowstart[base] = r;
        *(int4*)&cursor[base] = r;
    } else {
        for (int i = 0; i < 4; ++i) {
            if (base + i < n_nodes) {
                int r = local[base + i] + off;
                rowstart[base + i] = r;
                cursor[base + i] = r;
            }
        }
    }
}

// ---------------- C: dst-CSR fill (eidx=src), XCD-grouped --------------------
__global__ __launch_bounds__(256) void k_fill(
    const int* __restrict__ src, const int* __restrict__ dst,
    int* __restrict__ cursor, int* __restrict__ eidx, int n_edges, int n_nodes)
{
    int grp = blockIdx.x & (FILL_GRP - 1);
    int lo = (int)((long long)grp * n_nodes / FILL_GRP);
    int hi = (int)((long long)(grp + 1) * n_nodes / FILL_GRP);
    int nblk = gridDim.x >> 3;
    int bid = blockIdx.x >> 3;
    for (int e = bid * 256 + threadIdx.x; e < n_edges; e += nblk * 256) {
        int v = dst[e];
        if (v >= lo && v < hi) {
            int pos = atomicAdd(&cursor[v], 1);
            eidx[pos] = src[e];
        }
    }
}

// ---------------- C2: W scatter: Wint[src][g_dst] += wint_dst ---------------
// Native int atomics (no CAS). XCD-grouped by src: each pass's 3.2MB W slice
// stays L2-resident. pwg (400KB, read-only) caches in every XCD L2.
__global__ __launch_bounds__(256) void k_scatW(
    const int* __restrict__ src, const int* __restrict__ dst,
    const unsigned* __restrict__ pwg, int* __restrict__ Wint,
    int n_edges, int n_nodes)
{
    int grp = blockIdx.x & (FILL_GRP - 1);
    int lo = (int)((long long)grp * n_nodes / FILL_GRP);
    int hi = (int)((long long)(grp + 1) * n_nodes / FILL_GRP);
    int nblk = gridDim.x >> 3;
    int bid = blockIdx.x >> 3;
    for (int e = bid * 256 + threadIdx.x; e < n_edges; e += nblk * 256) {
        int s = src[e];
        if (s >= lo && s < hi) {
            unsigned p = pwg[dst[e]];
            atomicAdd(&Wint[(size_t)s * NGR + (p >> 24)], (int)(p & 0xFFFFFFu));
        }
    }
}

// ---------------- D: layer-1 gather, QUAD-PER-NODE (R8 form) -----------------
__global__ __launch_bounds__(256) void k_agg1(
    const int* __restrict__ rowstart, const int* __restrict__ eidx,
    const unsigned* __restrict__ fbd, const float* __restrict__ feat0,
    unsigned* __restrict__ hnbd, int n_nodes)
{
    int lane = threadIdx.x & 63;
    int quad = lane >> 4, l15 = lane & 15;
    int wglob = (int)((blockIdx.x * 256u + threadIdx.x) >> 6);
    int v = wglob * 4 + quad;
    if (v >= n_nodes) return;
    int e0 = rowstart[v], e1 = rowstart[v + 1];
    int nedge = e1 - e0;
    float a0 = 0.f, a1 = 0.f;
    for (int base = 0; base < nedge; base += 16) {
        int cnt = min(16, nedge - base);
        int idx = 0;
        if (l15 < cnt) idx = eidx[e0 + base + l15];
        unsigned uu[16];
#pragma unroll
        for (int j = 0; j < 16; ++j) {
            int s = __shfl(idx, quad * 16 + min(j, cnt - 1));
            uu[j] = 0u;
            if (j < cnt) uu[j] = fbd[(size_t)s * 16 + l15];
        }
#pragma unroll
        for (int j = 0; j < 16; ++j) {
            a0 += bf2f((unsigned short)(uu[j] & 0xFFFF));
            a1 += bf2f((unsigned short)(uu[j] >> 16));
        }
    }
    int d0 = 2 * l15, d1 = d0 + 1;
    float f0 = (d0 < IN_DIM) ? feat0[(size_t)v * IN_DIM + d0] : 0.f;
    float f1 = (d1 < IN_DIM) ? feat0[(size_t)v * IN_DIM + d1] : 0.f;
    float inv = 1.0f / ((float)nedge + 1.0f);
    unsigned out = (unsigned)f2bf((a0 + f0) * inv)
                 | ((unsigned)f2bf((a1 + f1) * inv) << 16);
    hnbd[(size_t)v * 16 + l15] = out;
}

// ---------------- E: MFMA node transform (unchanged) -------------------------
__global__ __launch_bounds__(256) void k_node(
    const unsigned short* __restrict__ hnb, const unsigned short* __restrict__ W1t,
    const float* __restrict__ b1, const unsigned short* __restrict__ W2t,
    unsigned short* __restrict__ m1, int n_nodes)
{
    __shared__ unsigned short ph[4][16 * PH_STRIDE];
    int wave = threadIdx.x >> 6, lane = threadIdx.x & 63;
    int quad = lane >> 4, l15 = lane & 15;
    const f32x4 z4 = {0.f, 0.f, 0.f, 0.f};

    float bb[8];
#pragma unroll
    for (int t = 0; t < 8; ++t) bb[t] = b1[t * 16 + l15];

    for (int v0 = blockIdx.x * 64 + wave * 16; v0 < n_nodes; v0 += gridDim.x * 64) {
        bf16x8 aH = {0, 0, 0, 0, 0, 0, 0, 0};
        int vA = v0 + l15;
        if (vA < n_nodes) aH = *(const bf16x8*)&hnb[(size_t)vA * FB_DIM + quad * 8];
        f32x4 c1[8];
#pragma unroll
        for (int t = 0; t < 8; ++t) {
            bf16x8 bw = *(const bf16x8*)&W1t[(t * 16 + l15) * 32 + quad * 8];
            c1[t] = __builtin_amdgcn_mfma_f32_16x16x32_bf16(aH, bw, z4, 0, 0, 0);
        }
        float ssq[4] = {0.f, 0.f, 0.f, 0.f};
#pragma unroll
        for (int t = 0; t < 8; ++t) {
#pragma unroll
            for (int r = 0; r < 4; ++r) {
                float x = fmaxf(c1[t][r] + bb[t], 0.f);
                c1[t][r] = x;
                ssq[r] += x * x;
            }
        }
#pragma unroll
        for (int off = 1; off < 16; off <<= 1) {
#pragma unroll
            for (int r = 0; r < 4; ++r) ssq[r] += __shfl_xor(ssq[r], off);
        }
        float inv[4];
#pragma unroll
        for (int r = 0; r < 4; ++r) inv[r] = 1.0f / fmaxf(sqrtf(ssq[r]), 1e-12f);
#pragma unroll
        for (int t = 0; t < 8; ++t)
#pragma unroll
            for (int r = 0; r < 4; ++r)
                ph[wave][(quad * 4 + r) * PH_STRIDE + t * 16 + l15] =
                    f2bf(c1[t][r] * inv[r]);
        f32x4 c2[4] = {z4, z4, z4, z4};
#pragma unroll
        for (int ks = 0; ks < 4; ++ks) {
            bf16x8 aP = *(const bf16x8*)&ph[wave][l15 * PH_STRIDE + ks * 32 + quad * 8];
#pragma unroll
            for (int tn = 0; tn < 4; ++tn) {
                bf16x8 bw = *(const bf16x8*)&W2t[(tn * 16 + l15) * HID + ks * 32 + quad * 8];
                c2[tn] = __builtin_amdgcn_mfma_f32_16x16x32_bf16(aP, bw, c2[tn], 0, 0, 0);
            }
        }
#pragma unroll
        for (int tn = 0; tn < 4; ++tn)
#pragma unroll
            for (int r = 0; r < 4; ++r) {
                int v = v0 + quad * 4 + r;
                if (v < n_nodes) m1[(size_t)v * OUTD + tn * 16 + l15] = f2bf(c2[tn][r]);
            }
    }
}

// ---------------- F: OUT[64x64] = W^T @ M1 via MFMA, K = n_nodes -------------
// A[m=g][k=u] = W[u][g] (transposed via LDS), B[k=u][n=d] = M1[u][d].
// 32-row K-steps; per step each of 4 waves does its 16-g m-block x 4 d-blocks
// = 4 MFMAs. LDS row stride 66 ushorts -> 2 lanes/bank (free). Sequential
// streaming only: ~25.6MB reads total.
__global__ __launch_bounds__(256) void k_gemm(
    const int* __restrict__ Wint, const unsigned short* __restrict__ m1,
    float* __restrict__ pb, int n_nodes)
{
    __shared__ unsigned short Wl[32 * 66];
    __shared__ unsigned short Ml[32 * 66];
    int wave = threadIdx.x >> 6, lane = threadIdx.x & 63;
    int quad = lane >> 4, l15 = lane & 15;
    const f32x4 z4 = {0.f, 0.f, 0.f, 0.f};
    f32x4 acc[4] = {z4, z4, z4, z4};
    const float inv_scale = 1.0f / WSCALE;

    int nsteps = (n_nodes + 31) >> 5;
    for (int s = blockIdx.x; s < nsteps; s += gridDim.x) {
        int u0 = s * 32;
        __syncthreads();   // protect LDS from previous step's readers
        for (int i = threadIdx.x; i < 2048; i += 256) {
            int r = i >> 6, c = i & 63;
            int u = u0 + r;
            float wv = 0.f;
            unsigned short mv = 0;
            if (u < n_nodes) {
                wv = (float)Wint[(size_t)u * NGR + c] * inv_scale;
                mv = m1[(size_t)u * OUTD + c];
            }
            Wl[r * 66 + c] = f2bf(wv);
            Ml[r * 66 + c] = mv;
        }
        __syncthreads();
        bf16x8 aF, bF;
#pragma unroll
        for (int j = 0; j < 8; ++j)
            aF[j] = (short)Wl[(quad * 8 + j) * 66 + wave * 16 + l15];
#pragma unroll
        for (int tn = 0; tn < 4; ++tn) {
#pragma unroll
            for (int j = 0; j < 8; ++j)
                bF[j] = (short)Ml[(quad * 8 + j) * 66 + tn * 16 + l15];
            acc[tn] = __builtin_amdgcn_mfma_f32_16x16x32_bf16(aF, bF, acc[tn], 0, 0, 0);
        }
    }
    // per-block partial: OUT[g][d], g = wave*16 + quad*4 + r, d = tn*16 + l15
    float* out = pb + (size_t)blockIdx.x * (NGR * OUTD);
#pragma unroll
    for (int tn = 0; tn < 4; ++tn)
#pragma unroll
        for (int r = 0; r < 4; ++r)
            out[(wave * 16 + quad * 4 + r) * OUTD + tn * 16 + l15] = acc[tn][r];
}

// ---------------- G: finalize: reduce partials, mean + b2 --------------------
__global__ __launch_bounds__(256) void k_final(
    const float* __restrict__ pb, const int* __restrict__ gcnt_i,
    const float* __restrict__ b2, float* __restrict__ out)
{
    int i = blockIdx.x * 256 + threadIdx.x;
    if (i >= NGR * OUTD) return;
    float s = 0.f;
    for (int p = 0; p < GEMM_BLKS; ++p) s += pb[(size_t)p * NGR * OUTD + i];
    int g = i >> 6, d = i & 63;
    int c = gcnt_i[g];
    out[i] = (c > 0) ? (s / (float)c + b2[d]) : 0.f;
}

extern "C" void kernel_launch(void* const* d_in, const int* in_sizes, int n_in,
                              void* d_out, int out_size, void* d_ws, size_t ws_size,
                              hipStream_t stream) {
    const float* feat0 = (const float*)d_in[0];
    const float* W1    = (const float*)d_in[1];
    const float* b1    = (const float*)d_in[2];
    const float* W2    = (const float*)d_in[3];
    const float* b2    = (const float*)d_in[4];
    const int*   src   = (const int*)d_in[5];
    const int*   dst   = (const int*)d_in[6];
    const int*   gids  = (const int*)d_in[7];
    int n_edges = in_sizes[5];
    int n_nodes = in_sizes[7];

    int nb = (n_nodes + 1023) / 1024;

    // workspace: bf16 section (16B-aligned) first, then 4B section with the
    // zeroed block (degi | Wint | gcnt_i) leading.
    unsigned short* W1t = (unsigned short*)d_ws;
    unsigned short* W2t = W1t + HID * 32;
    unsigned short* hnb = W2t + (size_t)OUTD * HID;
    unsigned short* m1b = hnb + (size_t)n_nodes * FB_DIM;
    unsigned short* featb = m1b + (size_t)n_nodes * OUTD;
    int*   degi     = (int*)(featb + (size_t)n_nodes * FB_DIM);
    int*   Wint     = degi + n_nodes;
    int*   gcnt_i   = Wint + (size_t)n_nodes * NGR;
    int*   rowstart = gcnt_i + NGR;
    int*   cursor   = rowstart + n_nodes + 1;
    int*   local    = cursor + n_nodes;
    int*   bsum     = local + n_nodes;
    int*   boff     = bsum + nb;
    int*   eidx     = boff + nb;
    unsigned* pwg   = (unsigned*)(eidx + n_edges);
    float* pb       = (float*)(pwg + n_nodes);

    size_t zero_units = (size_t)n_nodes * (1 + NGR) + NGR;
    hipMemsetAsync(degi, 0, zero_units * 4, stream);

    unsigned blkE = (unsigned)((n_edges + 255) / 256);
    k_hist<<<blkE, 256, 0, stream>>>(dst, degi, n_edges);

    k_featb<<<(unsigned)(((long long)n_nodes * FB_DIM + 255) / 256), 256, 0, stream>>>(
        feat0, featb, n_nodes);
    k_wprep<<<(HID * 32 + OUTD * HID + 255) / 256, 256, 0, stream>>>(W1, W2, W1t, W2t);
    k_pwg<<<(n_nodes + 255) / 256, 256, 0, stream>>>(degi, gids, pwg, Wint, gcnt_i,
                                                     n_nodes);

    k_scan_local<<<nb, 256, 0, stream>>>(degi, local, bsum, n_nodes);
    k_scan_bsum<<<1, 1024, 0, stream>>>(bsum, boff, rowstart, nb, n_nodes, n_edges);
    k_scan_apply<<<nb, 256, 0, stream>>>(local, boff, rowstart, cursor, n_nodes);

    k_fill<<<2048, 256, 0, stream>>>(src, dst, cursor, eidx, n_edges, n_nodes);
    k_scatW<<<2048, 256, 0, stream>>>(src, dst, pwg, Wint, n_edges, n_nodes);

    unsigned blkA = (unsigned)((n_nodes + 15) / 16);
    k_agg1<<<blkA, 256, 0, stream>>>(rowstart, eidx, (const unsigned*)featb, feat0,
                                     (unsigned*)hnb, n_nodes);

    k_node<<<1024, 256, 0, stream>>>(hnb, W1t, b1, W2t, m1b, n_nodes);

    k_gemm<<<GEMM_BLKS, 256, 0, stream>>>(Wint, m1b, pb, n_nodes);

    k_final<<<(NGR * OUTD + 255) / 256, 256, 0, stream>>>(pb, gcnt_i, b2, (float*)d_out);
}

// Round 13
// 399.681 us; speedup vs baseline: 2.7930x; 2.0576x over previous
//
#include <hip/hip_runtime.h>

#define IN_DIM 23
#define HID 128
#define OUTD 64
#define NGR 64
#define FILL_GRP 8
#define FB_DIM 32      // feat padded to 32 bf16 = 64B aligned rows
#define PH_STRIDE 136  // k_node LDS stride
#define WSCALE 8388608.0f   // 2^23 fixed-point scale for W
#define GEMM_BLKS 256

typedef __attribute__((ext_vector_type(8))) short bf16x8;
typedef __attribute__((ext_vector_type(4))) float f32x4;

static __device__ __forceinline__ unsigned short f2bf(float x) {
    unsigned u = __float_as_uint(x);
    unsigned r = (u + 0x7FFFu + ((u >> 16) & 1u)) >> 16;   // RNE
    return (unsigned short)r;
}
static __device__ __forceinline__ float bf2f(unsigned short u) {
    return __uint_as_float((unsigned)u << 16);             // exact
}

// ---------------- A: dst in-degree histogram (native int atomics) ------------
__global__ __launch_bounds__(256) void k_hist(
    const int* __restrict__ dst, int* __restrict__ degi, int n_edges)
{
    int e = blockIdx.x * 256 + threadIdx.x;
    if (e < n_edges) atomicAdd(&degi[dst[e]], 1);
}

// ---------------- A2: transcode feat0 -> bf16 padded rows --------------------
__global__ __launch_bounds__(256) void k_featb(
    const float* __restrict__ feat0, unsigned short* __restrict__ featb,
    int n_nodes)
{
    int i = blockIdx.x * 256 + threadIdx.x;
    if (i >= n_nodes * FB_DIM) return;
    int v = i >> 5, d = i & (FB_DIM - 1);
    float x = (d < IN_DIM) ? feat0[(size_t)v * IN_DIM + d] : 0.f;
    featb[i] = f2bf(x);
}

// ---------------- A3: weight transpose+pad to bf16 MFMA B-operand layout -----
__global__ __launch_bounds__(256) void k_wprep(
    const float* __restrict__ W1, const float* __restrict__ W2,
    unsigned short* __restrict__ W1t, unsigned short* __restrict__ W2t)
{
    int i = blockIdx.x * 256 + threadIdx.x;
    if (i < HID * 32) {
        int h = i >> 5, d = i & 31;
        W1t[i] = f2bf((d < IN_DIM) ? W1[d * HID + h] : 0.f);
    } else if (i < HID * 32 + OUTD * HID) {
        int j = i - HID * 32;
        int o = j >> 7, k = j & 127;
        W2t[j] = f2bf(W2[k * OUTD + o]);
    }
}

// ---------------- A4: payload pack (gid<<24)|wint + W self-term (plain store)
// gcnt moved to k_gcnt (sorted gids -> the old per-node atomic serialized on
// 64 addresses: 429us of same-address contention).
__global__ __launch_bounds__(256) void k_pwg(
    const int* __restrict__ degi, const int* __restrict__ gids,
    unsigned* __restrict__ pwg, int* __restrict__ Wint, int n_nodes)
{
    int v = blockIdx.x * 256 + threadIdx.x;
    if (v >= n_nodes) return;
    float w = 1.0f / ((float)degi[v] + 1.0f);
    int wi = (int)rintf(w * WSCALE);        // <= 2^23, fits 24 bits
    int g = gids[v];
    pwg[v] = ((unsigned)g << 24) | (unsigned)wi;
    Wint[(size_t)v * NGR + g] = wi;         // unique cell, buffer pre-zeroed
}

// ---------------- A5: per-graph node counts via binary search (sorted gids) --
__global__ __launch_bounds__(64) void k_gcnt(
    const int* __restrict__ gids, int* __restrict__ gcnt_i, int n_nodes)
{
    int g = threadIdx.x;
    if (g >= NGR) return;
    int lo0 = 0, hi0 = n_nodes;
    while (lo0 < hi0) { int m = (lo0 + hi0) >> 1; if (gids[m] < g) lo0 = m + 1; else hi0 = m; }
    int lo1 = lo0, hi1 = n_nodes;
    while (lo1 < hi1) { int m = (lo1 + hi1) >> 1; if (gids[m] < g + 1) lo1 = m + 1; else hi1 = m; }
    gcnt_i[g] = lo1 - lo0;
}

// ---------------- B1: per-block local exclusive scan + block totals ----------
__global__ __launch_bounds__(256) void k_scan_local(
    const int* __restrict__ degi, int* __restrict__ local,
    int* __restrict__ bsum, int n_nodes)
{
    int base = blockIdx.x * 1024 + threadIdx.x * 4;
    int4 d = {0, 0, 0, 0};
    if (base + 3 < n_nodes) {
        d = *(const int4*)&degi[base];
    } else {
        if (base + 0 < n_nodes) d.x = degi[base + 0];
        if (base + 1 < n_nodes) d.y = degi[base + 1];
        if (base + 2 < n_nodes) d.z = degi[base + 2];
        if (base + 3 < n_nodes) d.w = degi[base + 3];
    }
    int tsum = d.x + d.y + d.z + d.w;
    int lane = threadIdx.x & 63;
    int wave = threadIdx.x >> 6;
    int s = tsum;
#pragma unroll
    for (int off = 1; off < 64; off <<= 1) {
        int v = __shfl_up(s, off);
        if (lane >= off) s += v;
    }
    __shared__ int wtot[4];
    if (lane == 63) wtot[wave] = s;
    __syncthreads();
    int woff = 0;
#pragma unroll
    for (int i = 0; i < 4; ++i) woff += (i < wave) ? wtot[i] : 0;
    int excl = woff + s - tsum;
    int l0 = excl;
    int l1 = l0 + d.x;
    int l2 = l1 + d.y;
    int l3 = l2 + d.z;
    if (base + 3 < n_nodes) {
        *(int4*)&local[base] = make_int4(l0, l1, l2, l3);
    } else {
        if (base + 0 < n_nodes) local[base + 0] = l0;
        if (base + 1 < n_nodes) local[base + 1] = l1;
        if (base + 2 < n_nodes) local[base + 2] = l2;
        if (base + 3 < n_nodes) local[base + 3] = l3;
    }
    if (threadIdx.x == 255) bsum[blockIdx.x] = excl + tsum;
}

// ---------------- B2: scan the (<=1024) block totals -------------------------
__global__ __launch_bounds__(1024) void k_scan_bsum(
    const int* __restrict__ bsum, int* __restrict__ boff,
    int* __restrict__ rowstart, int nb, int n_nodes, int n_edges)
{
    __shared__ int lds[1024];
    int t = threadIdx.x;
    lds[t] = (t < nb) ? bsum[t] : 0;
    __syncthreads();
    for (int off = 1; off < 1024; off <<= 1) {
        int v = (t >= off) ? lds[t - off] : 0;
        __syncthreads();
        lds[t] += v;
        __syncthreads();
    }
    if (t < nb) boff[t] = (t == 0) ? 0 : lds[t - 1];
    if (t == 0) rowstart[n_nodes] = n_edges;
}

// ---------------- B3: apply block offsets -> rowstart, cursor ----------------
__global__ __launch_bounds__(256) void k_scan_apply(
    const int* __restrict__ local, const int* __restrict__ boff,
    int* __restrict__ rowstart, int* __restrict__ cursor, int n_nodes)
{
    int base = blockIdx.x * 1024 + threadIdx.x * 4;
    int off = boff[blockIdx.x];
    if (base + 3 < n_nodes) {
        int4 l = *(const int4*)&local[base];
        int4 r = make_int4(l.x + off, l.y + off, l.z + off, l.w + off);
        *(int4*)&rowstart[base] = r;
        *(int4*)&cursor[base] = r;
    } else {
        for (int i = 0; i < 4; ++i) {
            if (base + i < n_nodes) {
                int r = local[base + i] + off;
                rowstart[base + i] = r;
                cursor[base + i] = r;
            }
        }
    }
}

// ---------------- C: dst-CSR fill (eidx=src), XCD-grouped --------------------
__global__ __launch_bounds__(256) void k_fill(
    const int* __restrict__ src, const int* __restrict__ dst,
    int* __restrict__ cursor, int* __restrict__ eidx, int n_edges, int n_nodes)
{
    int grp = blockIdx.x & (FILL_GRP - 1);
    int lo = (int)((long long)grp * n_nodes / FILL_GRP);
    int hi = (int)((long long)(grp + 1) * n_nodes / FILL_GRP);
    int nblk = gridDim.x >> 3;
    int bid = blockIdx.x >> 3;
    for (int e = bid * 256 + threadIdx.x; e < n_edges; e += nblk * 256) {
        int v = dst[e];
        if (v >= lo && v < hi) {
            int pos = atomicAdd(&cursor[v], 1);
            eidx[pos] = src[e];
        }
    }
}

// ---------------- C2: W scatter: Wint[src][g_dst] += wint_dst ---------------
// Native int atomics (no CAS). XCD-grouped by src: each pass's 3.2MB W slice
// stays L2-resident. pwg (400KB, read-only) caches in every XCD L2.
__global__ __launch_bounds__(256) void k_scatW(
    const int* __restrict__ src, const int* __restrict__ dst,
    const unsigned* __restrict__ pwg, int* __restrict__ Wint,
    int n_edges, int n_nodes)
{
    int grp = blockIdx.x & (FILL_GRP - 1);
    int lo = (int)((long long)grp * n_nodes / FILL_GRP);
    int hi = (int)((long long)(grp + 1) * n_nodes / FILL_GRP);
    int nblk = gridDim.x >> 3;
    int bid = blockIdx.x >> 3;
    for (int e = bid * 256 + threadIdx.x; e < n_edges; e += nblk * 256) {
        int s = src[e];
        if (s >= lo && s < hi) {
            unsigned p = pwg[dst[e]];
            atomicAdd(&Wint[(size_t)s * NGR + (p >> 24)], (int)(p & 0xFFFFFFu));
        }
    }
}

// ---------------- D: layer-1 gather, QUAD-PER-NODE ---------------------------
__global__ __launch_bounds__(256) void k_agg1(
    const int* __restrict__ rowstart, const int* __restrict__ eidx,
    const unsigned* __restrict__ fbd, const float* __restrict__ feat0,
    unsigned* __restrict__ hnbd, int n_nodes)
{
    int lane = threadIdx.x & 63;
    int quad = lane >> 4, l15 = lane & 15;
    int wglob = (int)((blockIdx.x * 256u + threadIdx.x) >> 6);
    int v = wglob * 4 + quad;
    if (v >= n_nodes) return;
    int e0 = rowstart[v], e1 = rowstart[v + 1];
    int nedge = e1 - e0;
    float a0 = 0.f, a1 = 0.f;
    for (int base = 0; base < nedge; base += 16) {
        int cnt = min(16, nedge - base);
        int idx = 0;
        if (l15 < cnt) idx = eidx[e0 + base + l15];
        unsigned uu[16];
#pragma unroll
        for (int j = 0; j < 16; ++j) {
            int s = __shfl(idx, quad * 16 + min(j, cnt - 1));
            uu[j] = 0u;
            if (j < cnt) uu[j] = fbd[(size_t)s * 16 + l15];
        }
#pragma unroll
        for (int j = 0; j < 16; ++j) {
            a0 += bf2f((unsigned short)(uu[j] & 0xFFFF));
            a1 += bf2f((unsigned short)(uu[j] >> 16));
        }
    }
    int d0 = 2 * l15, d1 = d0 + 1;
    float f0 = (d0 < IN_DIM) ? feat0[(size_t)v * IN_DIM + d0] : 0.f;
    float f1 = (d1 < IN_DIM) ? feat0[(size_t)v * IN_DIM + d1] : 0.f;
    float inv = 1.0f / ((float)nedge + 1.0f);
    unsigned out = (unsigned)f2bf((a0 + f0) * inv)
                 | ((unsigned)f2bf((a1 + f1) * inv) << 16);
    hnbd[(size_t)v * 16 + l15] = out;
}

// ---------------- E: MFMA node transform (unchanged) -------------------------
__global__ __launch_bounds__(256) void k_node(
    const unsigned short* __restrict__ hnb, const unsigned short* __restrict__ W1t,
    const float* __restrict__ b1, const unsigned short* __restrict__ W2t,
    unsigned short* __restrict__ m1, int n_nodes)
{
    __shared__ unsigned short ph[4][16 * PH_STRIDE];
    int wave = threadIdx.x >> 6, lane = threadIdx.x & 63;
    int quad = lane >> 4, l15 = lane & 15;
    const f32x4 z4 = {0.f, 0.f, 0.f, 0.f};

    float bb[8];
#pragma unroll
    for (int t = 0; t < 8; ++t) bb[t] = b1[t * 16 + l15];

    for (int v0 = blockIdx.x * 64 + wave * 16; v0 < n_nodes; v0 += gridDim.x * 64) {
        bf16x8 aH = {0, 0, 0, 0, 0, 0, 0, 0};
        int vA = v0 + l15;
        if (vA < n_nodes) aH = *(const bf16x8*)&hnb[(size_t)vA * FB_DIM + quad * 8];
        f32x4 c1[8];
#pragma unroll
        for (int t = 0; t < 8; ++t) {
            bf16x8 bw = *(const bf16x8*)&W1t[(t * 16 + l15) * 32 + quad * 8];
            c1[t] = __builtin_amdgcn_mfma_f32_16x16x32_bf16(aH, bw, z4, 0, 0, 0);
        }
        float ssq[4] = {0.f, 0.f, 0.f, 0.f};
#pragma unroll
        for (int t = 0; t < 8; ++t) {
#pragma unroll
            for (int r = 0; r < 4; ++r) {
                float x = fmaxf(c1[t][r] + bb[t], 0.f);
                c1[t][r] = x;
                ssq[r] += x * x;
            }
        }
#pragma unroll
        for (int off = 1; off < 16; off <<= 1) {
#pragma unroll
            for (int r = 0; r < 4; ++r) ssq[r] += __shfl_xor(ssq[r], off);
        }
        float inv[4];
#pragma unroll
        for (int r = 0; r < 4; ++r) inv[r] = 1.0f / fmaxf(sqrtf(ssq[r]), 1e-12f);
#pragma unroll
        for (int t = 0; t < 8; ++t)
#pragma unroll
            for (int r = 0; r < 4; ++r)
                ph[wave][(quad * 4 + r) * PH_STRIDE + t * 16 + l15] =
                    f2bf(c1[t][r] * inv[r]);
        f32x4 c2[4] = {z4, z4, z4, z4};
#pragma unroll
        for (int ks = 0; ks < 4; ++ks) {
            bf16x8 aP = *(const bf16x8*)&ph[wave][l15 * PH_STRIDE + ks * 32 + quad * 8];
#pragma unroll
            for (int tn = 0; tn < 4; ++tn) {
                bf16x8 bw = *(const bf16x8*)&W2t[(tn * 16 + l15) * HID + ks * 32 + quad * 8];
                c2[tn] = __builtin_amdgcn_mfma_f32_16x16x32_bf16(aP, bw, c2[tn], 0, 0, 0);
            }
        }
#pragma unroll
        for (int tn = 0; tn < 4; ++tn)
#pragma unroll
            for (int r = 0; r < 4; ++r) {
                int v = v0 + quad * 4 + r;
                if (v < n_nodes) m1[(size_t)v * OUTD + tn * 16 + l15] = f2bf(c2[tn][r]);
            }
    }
}

// ---------------- F: OUT[64x64] = W^T @ M1 via MFMA, K = n_nodes -------------
__global__ __launch_bounds__(256) void k_gemm(
    const int* __restrict__ Wint, const unsigned short* __restrict__ m1,
    float* __restrict__ pb, int n_nodes)
{
    __shared__ unsigned short Wl[32 * 66];
    __shared__ unsigned short Ml[32 * 66];
    int wave = threadIdx.x >> 6, lane = threadIdx.x & 63;
    int quad = lane >> 4, l15 = lane & 15;
    const f32x4 z4 = {0.f, 0.f, 0.f, 0.f};
    f32x4 acc[4] = {z4, z4, z4, z4};
    const float inv_scale = 1.0f / WSCALE;

    int nsteps = (n_nodes + 31) >> 5;
    for (int s = blockIdx.x; s < nsteps; s += gridDim.x) {
        int u0 = s * 32;
        __syncthreads();   // protect LDS from previous step's readers
        for (int i = threadIdx.x; i < 2048; i += 256) {
            int r = i >> 6, c = i & 63;
            int u = u0 + r;
            float wv = 0.f;
            unsigned short mv = 0;
            if (u < n_nodes) {
                wv = (float)Wint[(size_t)u * NGR + c] * inv_scale;
                mv = m1[(size_t)u * OUTD + c];
            }
            Wl[r * 66 + c] = f2bf(wv);
            Ml[r * 66 + c] = mv;
        }
        __syncthreads();
        bf16x8 aF, bF;
#pragma unroll
        for (int j = 0; j < 8; ++j)
            aF[j] = (short)Wl[(quad * 8 + j) * 66 + wave * 16 + l15];
#pragma unroll
        for (int tn = 0; tn < 4; ++tn) {
#pragma unroll
            for (int j = 0; j < 8; ++j)
                bF[j] = (short)Ml[(quad * 8 + j) * 66 + tn * 16 + l15];
            acc[tn] = __builtin_amdgcn_mfma_f32_16x16x32_bf16(aF, bF, acc[tn], 0, 0, 0);
        }
    }
    float* out = pb + (size_t)blockIdx.x * (NGR * OUTD);
#pragma unroll
    for (int tn = 0; tn < 4; ++tn)
#pragma unroll
        for (int r = 0; r < 4; ++r)
            out[(wave * 16 + quad * 4 + r) * OUTD + tn * 16 + l15] = acc[tn][r];
}

// ---------------- G: finalize: reduce partials, mean + b2 --------------------
__global__ __launch_bounds__(256) void k_final(
    const float* __restrict__ pb, const int* __restrict__ gcnt_i,
    const float* __restrict__ b2, float* __restrict__ out)
{
    int i = blockIdx.x * 256 + threadIdx.x;
    if (i >= NGR * OUTD) return;
    float s = 0.f;
    for (int p = 0; p < GEMM_BLKS; ++p) s += pb[(size_t)p * NGR * OUTD + i];
    int g = i >> 6, d = i & 63;
    int c = gcnt_i[g];
    out[i] = (c > 0) ? (s / (float)c + b2[d]) : 0.f;
}

extern "C" void kernel_launch(void* const* d_in, const int* in_sizes, int n_in,
                              void* d_out, int out_size, void* d_ws, size_t ws_size,
                              hipStream_t stream) {
    const float* feat0 = (const float*)d_in[0];
    const float* W1    = (const float*)d_in[1];
    const float* b1    = (const float*)d_in[2];
    const float* W2    = (const float*)d_in[3];
    const float* b2    = (const float*)d_in[4];
    const int*   src   = (const int*)d_in[5];
    const int*   dst   = (const int*)d_in[6];
    const int*   gids  = (const int*)d_in[7];
    int n_edges = in_sizes[5];
    int n_nodes = in_sizes[7];

    int nb = (n_nodes + 1023) / 1024;

    // workspace: bf16 section (16B-aligned) first, then 4B section with the
    // zeroed block (degi | Wint) leading.
    unsigned short* W1t = (unsigned short*)d_ws;
    unsigned short* W2t = W1t + HID * 32;
    unsigned short* hnb = W2t + (size_t)OUTD * HID;
    unsigned short* m1b = hnb + (size_t)n_nodes * FB_DIM;
    unsigned short* featb = m1b + (size_t)n_nodes * OUTD;
    int*   degi     = (int*)(featb + (size_t)n_nodes * FB_DIM);
    int*   Wint     = degi + n_nodes;
    int*   gcnt_i   = Wint + (size_t)n_nodes * NGR;
    int*   rowstart = gcnt_i + NGR;
    int*   cursor   = rowstart + n_nodes + 1;
    int*   local    = cursor + n_nodes;
    int*   bsum     = local + n_nodes;
    int*   boff     = bsum + nb;
    int*   eidx     = boff + nb;
    unsigned* pwg   = (unsigned*)(eidx + n_edges);
    float* pb       = (float*)(pwg + n_nodes);

    size_t zero_units = (size_t)n_nodes * (1 + NGR);
    hipMemsetAsync(degi, 0, zero_units * 4, stream);

    unsigned blkE = (unsigned)((n_edges + 255) / 256);
    k_hist<<<blkE, 256, 0, stream>>>(dst, degi, n_edges);

    k_featb<<<(unsigned)(((long long)n_nodes * FB_DIM + 255) / 256), 256, 0, stream>>>(
        feat0, featb, n_nodes);
    k_wprep<<<(HID * 32 + OUTD * HID + 255) / 256, 256, 0, stream>>>(W1, W2, W1t, W2t);
    k_pwg<<<(n_nodes + 255) / 256, 256, 0, stream>>>(degi, gids, pwg, Wint, n_nodes);
    k_gcnt<<<1, 64, 0, stream>>>(gids, gcnt_i, n_nodes);

    k_scan_local<<<nb, 256, 0, stream>>>(degi, local, bsum, n_nodes);
    k_scan_bsum<<<1, 1024, 0, stream>>>(bsum, boff, rowstart, nb, n_nodes, n_edges);
    k_scan_apply<<<nb, 256, 0, stream>>>(local, boff, rowstart, cursor, n_nodes);

    k_fill<<<2048, 256, 0, stream>>>(src, dst, cursor, eidx, n_edges, n_nodes);
    k_scatW<<<2048, 256, 0, stream>>>(src, dst, pwg, Wint, n_edges, n_nodes);

    unsigned blkA = (unsigned)((n_nodes + 15) / 16);
    k_agg1<<<blkA, 256, 0, stream>>>(rowstart, eidx, (const unsigned*)featb, feat0,
                                     (unsigned*)hnb, n_nodes);

    k_node<<<1024, 256, 0, stream>>>(hnb, W1t, b1, W2t, m1b, n_nodes);

    k_gemm<<<GEMM_BLKS, 256, 0, stream>>>(Wint, m1b, pb, n_nodes);

    k_final<<<(NGR * OUTD + 255) / 256, 256, 0, stream>>>(pb, gcnt_i, b2, (float*)d_out);
}